// Round 14
// baseline (173.856 us; speedup 1.0000x reference)
//
#include <hip/hip_runtime.h>
#include <math.h>

// ---------------------------------------------------------------------------
// PreLossSampler (N=1024):
//   out = [reg_valid | labels | max_overlaps | gt_assignment]  (4096 float32)
//
// 3 kernels:
//   prep_sa   : 256x256, wave-per-element stable rank sort; writes
//               rankinv[e], sorted sbox/circ_s, circles, elementwise outs.
//   supA_sa   : 256x256, block owns 4 sorted rows; circle scan -> LDS pair
//               buffer -> dense clip eval -> LDS atomicOr -> global sup.
//   outB_fused: 256x256. Phase 1 (wave 0): greedy NMS, r13 LDS-ssup form
//               but with the 16-word loop NOT unrolled (#pragma unroll 1).
//               Hypothesis being tested: the fully-unrolled loop (~8K inst,
//               ~64 KB) thrashes the 32 KB I$ — a serial wave streaming
//               64 KB of code at ~200cyc/line explains the persistent 3-5x
//               gap between cycle models (12-17us) and measurements
//               (47-86us) across rounds 9-13. Dynamic W requires LDS for
//               ssup[W]/ksh[W] (r13 design); row[]/rb[] keep static inner
//               indices with dynamic predicates; diagonal loaded directly
//               (issued first -> early vmcnt release).
//               Phase 2: pred x gt scan (sampled via rankinv bit lookup) ->
//               LDS buffer -> dense IoU3D eval -> packed u64 atomicMax ->
//               out[2], out[3].
//
// Exactness: identical arithmetic to the absmax-0.0-validated rounds 6-13
// (clip, circle reject, rank predicate, batched cndmask NMS chain; ssup[W]
// == OR of kept rows' word W from words < W; same-wave LDS program-order
// visibility — no barriers in phase 1).
// ---------------------------------------------------------------------------

#define NB 1024

typedef unsigned long long u64;

__device__ __forceinline__ bool pt_in_box(float px, float py,
        float bx, float by, float bdx, float bdy, float cs, float sn) {
    float dx = px - bx, dy = py - by;
    float lx = dx * cs + dy * sn;
    float ly = dy * cs - dx * sn;
    return (fabsf(lx) <= bdx * 0.5f + 1e-5f) && (fabsf(ly) <= bdy * 0.5f + 1e-5f);
}

__device__ __forceinline__ unsigned sortbits(float f) {
    unsigned u = __float_as_uint(f + 0.0f);
    return (u & 0x80000000u) ? ~u : (u | 0x80000000u);
}

// Rotated-rectangle intersection area; reference-exact op order; all arrays
// <= 96 B, statically indexed (register-resident, zero scratch).
// Validated absmax 0.0.
__device__ float rect_inter_area(
        float ax, float ay, float adx, float ady, float ar,
        float bx, float by, float bdx, float bdy, float br) {
    float dcx = ax - bx, dcy = ay - by;
    float ra = 0.5f * sqrtf(adx * adx + ady * ady);
    float rb = 0.5f * sqrtf(bdx * bdx + bdy * bdy);
    float lim = ra + rb + 1e-3f;
    if (dcx * dcx + dcy * dcy > lim * lim) return 0.0f;

    float csa = cosf(ar), sna = sinf(ar);
    float csb = cosf(br), snb = sinf(br);
    float cax[4], cay[4], cbx[4], cby[4];
    const float SX[4] = {0.5f, 0.5f, -0.5f, -0.5f};
    const float SY[4] = {0.5f, -0.5f, -0.5f, 0.5f};
#pragma unroll
    for (int i = 0; i < 4; ++i) {
        float lx = SX[i] * adx, ly = SY[i] * ady;
        cax[i] = lx * csa - ly * sna + ax;
        cay[i] = lx * sna + ly * csa + ay;
        float mx = SX[i] * bdx, my = SY[i] * bdy;
        cbx[i] = mx * csb - my * snb + bx;
        cby[i] = mx * snb + my * csb + by;
    }

    unsigned vmask = 0u;
    float sx = 0.0f, sy = 0.0f;
#pragma unroll
    for (int i = 0; i < 4; ++i) {
        bool v = pt_in_box(cax[i], cay[i], bx, by, bdx, bdy, csb, snb);
        vmask |= v ? (1u << i) : 0u;
        sx += v ? cax[i] : 0.0f;
        sy += v ? cay[i] : 0.0f;
    }
#pragma unroll
    for (int i = 0; i < 4; ++i) {
        bool v = pt_in_box(cbx[i], cby[i], ax, ay, adx, ady, csa, sna);
        vmask |= v ? (1u << (4 + i)) : 0u;
        sx += v ? cbx[i] : 0.0f;
        sy += v ? cby[i] : 0.0f;
    }
#pragma unroll
    for (int i = 0; i < 4; ++i) {
        float a0x = cax[i], a0y = cay[i];
        float d1x = cax[(i + 1) & 3] - a0x, d1y = cay[(i + 1) & 3] - a0y;
#pragma unroll
        for (int j = 0; j < 4; ++j) {
            int s = 8 + i * 4 + j;
            float b0x = cbx[j], b0y = cby[j];
            float d2x = cbx[(j + 1) & 3] - b0x, d2y = cby[(j + 1) & 3] - b0y;
            float r0x = b0x - a0x, r0y = b0y - a0y;
            float den = d1x * d2y - d1y * d2x;
            bool nz = fabsf(den) > 1e-8f;
            float sden = nz ? den : 1.0f;
            float t = (r0x * d2y - r0y * d2x) / sden;
            float u = (r0x * d1y - r0y * d1x) / sden;
            bool ok = nz && t >= 0.0f && t <= 1.0f && u >= 0.0f && u <= 1.0f;
            float ipx = a0x + t * d1x;
            float ipy = a0y + t * d1y;
            vmask |= ok ? (1u << s) : 0u;
            sx += ok ? ipx : 0.0f;
            sy += ok ? ipy : 0.0f;
        }
    }
    int kc = __popc(vmask);
    if (kc < 3) return 0.0f;
    float ctrx = sx / (float)kc, ctry = sy / (float)kc;

    float cx24[24], cy24[24];
    unsigned h[24];
#pragma unroll
    for (int i = 0; i < 4; ++i) {
        {
            bool v = (vmask >> i) & 1u;
            float cx = v ? cax[i] - ctrx : 0.0f;
            float cy = v ? cay[i] - ctry : 0.0f;
            cx24[i] = cx; cy24[i] = cy;
            h[i] = sortbits(v ? atan2f(cy, cx) : 1e9f);
        }
        {
            bool v = (vmask >> (4 + i)) & 1u;
            float cx = v ? cbx[i] - ctrx : 0.0f;
            float cy = v ? cby[i] - ctry : 0.0f;
            cx24[4 + i] = cx; cy24[4 + i] = cy;
            h[4 + i] = sortbits(v ? atan2f(cy, cx) : 1e9f);
        }
    }
#pragma unroll
    for (int i = 0; i < 4; ++i) {
        float a0x = cax[i], a0y = cay[i];
        float d1x = cax[(i + 1) & 3] - a0x, d1y = cay[(i + 1) & 3] - a0y;
#pragma unroll
        for (int j = 0; j < 4; ++j) {
            int s = 8 + i * 4 + j;
            float b0x = cbx[j], b0y = cby[j];
            float d2x = cbx[(j + 1) & 3] - b0x, d2y = cby[(j + 1) & 3] - b0y;
            float r0x = b0x - a0x, r0y = b0y - a0y;
            float den = d1x * d2y - d1y * d2x;
            bool nz = fabsf(den) > 1e-8f;
            float sden = nz ? den : 1.0f;
            float t = (r0x * d2y - r0y * d2x) / sden;
            bool v = (vmask >> s) & 1u;
            float ipx = a0x + t * d1x;
            float ipy = a0y + t * d1y;
            float cx = v ? ipx - ctrx : 0.0f;
            float cy = v ? ipy - ctry : 0.0f;
            cx24[s] = cx; cy24[s] = cy;
            h[s] = sortbits(v ? atan2f(cy, cx) : 1e9f);
        }
    }

    int rk[24];
#pragma unroll
    for (int s = 0; s < 24; ++s) rk[s] = 0;
#pragma unroll
    for (int s = 0; s < 24; ++s) {
#pragma unroll
        for (int t = s + 1; t < 24; ++t) {
            bool a = h[s] <= h[t];
            rk[t] += a ? 1 : 0;
            rk[s] += a ? 0 : 1;
        }
    }

    float acc = 0.0f;
    float fx = 0.0f, fy = 0.0f, lx2 = 0.0f, ly2 = 0.0f;
    float pxp = 0.0f, pyp = 0.0f;
#pragma unroll
    for (int p = 0; p < 24; ++p) {
        float X = 0.0f, Y = 0.0f;
#pragma unroll
        for (int s = 0; s < 24; ++s) {
            bool m = (rk[s] == p);
            X = m ? cx24[s] : X;
            Y = m ? cy24[s] : Y;
        }
        if (p == 0) {
            fx = X; fy = Y;
        } else {
            float cr = pxp * Y - pyp * X;
            acc += (p < kc) ? cr : 0.0f;
        }
        bool e = (p == kc - 1);
        lx2 = e ? X : lx2;
        ly2 = e ? Y : ly2;
        pxp = X; pyp = Y;
    }
    acc += lx2 * fy - ly2 * fx;
    return 0.5f * fabsf(acc);
}

// ---------------------------------------------------------------------------
// prep_sa: 256x256. Wave (global id) handles element e; lane counts 16 keys;
// butterfly sum -> stable rank. Writes rankinv[e]=rank, sorted sbox/circ_s,
// circles, elementwise outs. (Validated rounds 9-13.)
// ---------------------------------------------------------------------------
__global__ __launch_bounds__(256) void prep_sa_kernel(
        const float* __restrict__ labels, const float* __restrict__ pred,
        const float* __restrict__ gt, const float* __restrict__ cls,
        float* __restrict__ out, int* __restrict__ rankinv,
        float* __restrict__ sbox, float4* __restrict__ circ_s,
        float4* __restrict__ circ_g, float4* __restrict__ circ_p) {
    int tid = threadIdx.x;
    int lane = tid & 63;
    int e = ((int)blockIdx.x * 256 + tid) >> 6;  // global wave id = element
    float ke = labels[e];
    const float4* lab4 = (const float4*)labels;
    int cntr = 0;
#pragma unroll
    for (int kk = 0; kk < 4; ++kk) {
        float4 kv = lab4[lane * 4 + kk];
        int t0 = lane * 16 + kk * 4;
        cntr += ((kv.x > ke) || (kv.x == ke && (t0 + 0) < e)) ? 1 : 0;
        cntr += ((kv.y > ke) || (kv.y == ke && (t0 + 1) < e)) ? 1 : 0;
        cntr += ((kv.z > ke) || (kv.z == ke && (t0 + 2) < e)) ? 1 : 0;
        cntr += ((kv.w > ke) || (kv.w == ke && (t0 + 3) < e)) ? 1 : 0;
    }
#pragma unroll
    for (int off = 32; off > 0; off >>= 1) cntr += __shfl_xor(cntr, off, 64);
    int rank = cntr;  // stable argsort(-labels) position of e
    if (lane < 7) sbox[rank * 8 + lane] = gt[e * 8 + lane];
    if (lane == 7) sbox[rank * 8 + 7] = 0.0f;
    if (lane == 0) {
        rankinv[e] = rank;
        float gdx = gt[e * 8 + 3], gdy = gt[e * 8 + 4];
        float4 cgc = make_float4(gt[e * 8 + 0], gt[e * 8 + 1],
                                 0.5f * sqrtf(gdx * gdx + gdy * gdy), 0.0f);
        circ_s[rank] = cgc;
        circ_g[e] = cgc;
        float pdx = pred[e * 7 + 3], pdy = pred[e * 7 + 4];
        circ_p[e] = make_float4(pred[e * 7 + 0], pred[e * 7 + 1],
                                0.5f * sqrtf(pdx * pdx + pdy * pdy), 0.0f);
        float sig = 1.0f / (1.0f + expf(-cls[e]));
        out[e] = (sig > 0.55f && ke > 0.55f) ? 1.0f : 0.0f;
        out[NB + e] = ke;
    }
}

// ---------------------------------------------------------------------------
// supA_sa: block b owns sorted rows i = b + 256v (v = wave). Circle scan ->
// LDS buffer (worst case 2556 <= 4096) -> dense clip eval -> LDS atomicOr ->
// global sup (all 16 words of all 4 rows written). Validated rounds 9-13.
// ---------------------------------------------------------------------------
__global__ __launch_bounds__(256) void supA_sa_kernel(
        const float* __restrict__ sbox, const float4* __restrict__ circ_s,
        u64* __restrict__ sup) {
    __shared__ unsigned ring[4096];
    __shared__ unsigned cnt_s;
    __shared__ unsigned sup32[128];
    int tid = threadIdx.x;
    int b = blockIdx.x;
    int lane = tid & 63;
    int wv = tid >> 6;
    if (tid == 0) cnt_s = 0u;
    for (int t = tid; t < 128; t += 256) sup32[t] = 0u;
    __syncthreads();
    {
        int i = b + (wv << 8);
        float4 A = circ_s[i];
        int j0 = ((i + 1) >> 6) << 6;
        for (int jb = j0; jb < 1024; jb += 64) {
            int j = jb + lane;
            bool q = j > i;
            if (q) {
                float4 B = circ_s[j];
                float dx = A.x - B.x, dy = A.y - B.y;
                float lim = A.z + B.z + 1e-3f;
                q = (dx * dx + dy * dy) <= lim * lim;
            }
            if (q) {
                unsigned pos = atomicAdd(&cnt_s, 1u);
                ring[pos] = (unsigned)((i << 10) | j);
            }
        }
    }
    __syncthreads();
    {
        unsigned n = cnt_s;
        for (unsigned t = tid; t < n; t += 256) {
            unsigned p = ring[t];
            int i = (p >> 10) & 1023, j = p & 1023;
            const float* A = &sbox[i * 8];
            const float* B = &sbox[j * 8];
            float inter = rect_inter_area(A[0], A[1], A[3], A[4], A[6],
                                          B[0], B[1], B[3], B[4], B[6]);
            float iou = inter / fmaxf(A[3] * A[4] + B[3] * B[4] - inter, 1e-8f);
            if (iou > 0.1f) {
                int r = (i - b) >> 8;
                atomicOr(&sup32[r * 32 + (j >> 5)], 1u << (j & 31));
            }
        }
    }
    __syncthreads();
    for (int t = tid; t < 64; t += 256) {
        int r = t >> 4, w = t & 15;
        int i = b + (r << 8);
        sup[i * 16 + w] = (u64)sup32[r * 32 + 2 * w] |
                          ((u64)sup32[r * 32 + 2 * w + 1] << 32);
    }
}

// ---------------------------------------------------------------------------
// outB_fused: phase 1 (wave 0) = greedy NMS with a NON-UNROLLED word loop
// (I$-resident body). Per word W (dynamic): diag + predicated row loads
// issued up front (diag first -> early vmcnt release); bc broadcast; kwW =
// ~ssup[W]; batched 64-step cndmask chain; kept lanes OR register rows into
// ssup (LDS atomics, dynamic predicate t > W). Phase 2 = pred x gt scan
// (sampled via rankinv bit lookup in ksh) -> LDS buffer -> dense IoU3D
// eval -> packed u64 atomicMax -> out[2], out[3].
// ---------------------------------------------------------------------------
__global__ __launch_bounds__(256) void outB_fused_kernel(
        const float* __restrict__ pred, const float* __restrict__ gt,
        const int* __restrict__ rankinv, const float4* __restrict__ circ_p,
        const float4* __restrict__ circ_g, const u64* __restrict__ sup,
        float* __restrict__ out) {
    __shared__ unsigned ring[4096];
    __shared__ unsigned cnt_s;
    __shared__ u64 bc[64];
    __shared__ u64 ssup[16];
    __shared__ u64 ksh[16];
    __shared__ u64 rm[4];
    int tid = threadIdx.x;
    int b = blockIdx.x;
    int lane = tid & 63;
    int wv = tid >> 6;
    if (tid == 0) cnt_s = 0u;
    if (tid < 4) rm[tid] = 1023ULL;  // pack(iou=0.0f, j=0)

    // ---- phase 1: NMS (wave 0 only; same-wave LDS -> program order) ----
    if (tid < 64) {
        if (lane < 16) ssup[lane] = 0ULL;
#pragma unroll 1
        for (int W = 0; W < 16; ++W) {
            const u64* myrow = &sup[(size_t)(W * 64 + lane) * 16];
            // diagonal first (earliest vmcnt release), then rows t > W
            u64 diag = myrow[W];
            u64 row[16];
#pragma unroll
            for (int t = 0; t < 16; ++t)
                row[t] = (t > W) ? myrow[t] : 0ULL;
            bc[lane] = diag;
            // cross-word suppression accumulated by prior words
            u64 kwW = ~ssup[W];
            // intra-word greedy: 64-step cndmask chain, reads batched 16
#pragma unroll
            for (int g = 0; g < 4; ++g) {
                u64 rb[16];
#pragma unroll
                for (int t = 0; t < 16; ++t) rb[t] = bc[g * 16 + t];
#pragma unroll
                for (int t = 0; t < 16; ++t) {
                    int bb = g * 16 + t;
                    bool kb = (kwW >> bb) & 1ULL;
                    kwW &= kb ? ~rb[t] : ~0ULL;
                }
            }
            if (lane == 0) ksh[W] = kwW;
            // kept lanes OR their register rows into ssup (order-free)
            bool me = (kwW >> lane) & 1ULL;
            if (me) {
#pragma unroll
                for (int t = 0; t < 16; ++t) {
                    if (t > W && row[t]) atomicOr(&ssup[t], row[t]);
                }
            }
        }
    }
    __syncthreads();

    // ---- phase 2: scan + eval ----
    {
        int i = b + (wv << 8);
        float4 A = circ_p[i];
        for (int jb = 0; jb < 1024; jb += 64) {
            int j = jb + lane;
            int r = rankinv[j];
            bool q = (ksh[r >> 6] >> (r & 63)) & 1ULL;  // sampled[j]
            if (q) {
                float4 B = circ_g[j];
                float dx = A.x - B.x, dy = A.y - B.y;
                float lim = A.z + B.z + 1e-3f;
                q = (dx * dx + dy * dy) <= lim * lim;
            }
            if (q) {
                unsigned pos = atomicAdd(&cnt_s, 1u);
                ring[pos] = (unsigned)((i << 10) | j);
            }
        }
    }
    __syncthreads();
    {
        unsigned n = cnt_s;
        for (unsigned t = tid; t < n; t += 256) {
            unsigned p = ring[t];
            int i = (p >> 10) & 1023, j = p & 1023;
            float Ax = pred[i * 7 + 0], Ay = pred[i * 7 + 1], Az = pred[i * 7 + 2];
            float Adx = pred[i * 7 + 3], Ady = pred[i * 7 + 4], Adz = pred[i * 7 + 5];
            float Ar = pred[i * 7 + 6];
            float Bx = gt[j * 8 + 0], By = gt[j * 8 + 1], Bz = gt[j * 8 + 2];
            float Bdx = gt[j * 8 + 3], Bdy = gt[j * 8 + 4], Bdz = gt[j * 8 + 5];
            float Br = gt[j * 8 + 6];
            float inter = rect_inter_area(Ax, Ay, Adx, Ady, Ar,
                                          Bx, By, Bdx, Bdy, Br);
            float amax = Az + Adz * 0.5f, amin = Az - Adz * 0.5f;
            float bmax = Bz + Bdz * 0.5f, bmin = Bz - Bdz * 0.5f;
            float oh = fmaxf(fminf(amax, bmax) - fmaxf(amin, bmin), 0.0f);
            float inter3d = inter * oh;
            float va = Adx * Ady * Adz, vb = Bdx * Bdy * Bdz;
            float iou = inter3d / fmaxf(va + vb - inter3d, 1e-8f);
            u64 pk = (((u64)__float_as_uint(iou)) << 32) | (u64)(1023 - j);
            int r = (i - b) >> 8;
            atomicMax(&rm[r], pk);
        }
    }
    __syncthreads();
    if (tid < 4) {
        int i = b + (tid << 8);
        u64 v = rm[tid];
        float fv = __uint_as_float((unsigned)(v >> 32));
        int j = 1023 - (int)(v & 0xFFFFFFFFULL);
        float mo = (fv > 0.75f) ? 1.0f : ((fv < 0.25f) ? 0.0f : fv);
        out[2 * NB + i] = mo;
        out[3 * NB + i] = (float)j;
    }
}

// ---------------------------------------------------------------------------
// Workspace layout:
//   [0,       4096)    int   rankinv[1024]
//   [4096,    36864)   float sbox[1024*8]
//   [40960,   172032)  u64   sup[1024*16]
//   [172032,  188416)  float4 circ_s[1024]
//   [188416,  204800)  float4 circ_g[1024]
//   [204800,  221184)  float4 circ_p[1024]
// ---------------------------------------------------------------------------
extern "C" void kernel_launch(void* const* d_in, const int* in_sizes, int n_in,
                              void* d_out, int out_size, void* d_ws, size_t ws_size,
                              hipStream_t stream) {
    const float* labels = (const float*)d_in[0];
    const float* pred   = (const float*)d_in[1];
    const float* gt     = (const float*)d_in[2];
    const float* cls    = (const float*)d_in[3];
    float* out = (float*)d_out;

    char* ws = (char*)d_ws;
    int* rankinv   = (int*)ws;
    float* sbox    = (float*)(ws + 4096);
    u64* sup       = (u64*)(ws + 40960);
    float4* circ_s = (float4*)(ws + 172032);
    float4* circ_g = (float4*)(ws + 188416);
    float4* circ_p = (float4*)(ws + 204800);

    prep_sa_kernel<<<256, 256, 0, stream>>>(labels, pred, gt, cls, out,
                                            rankinv, sbox, circ_s, circ_g,
                                            circ_p);
    supA_sa_kernel<<<256, 256, 0, stream>>>(sbox, circ_s, sup);
    outB_fused_kernel<<<256, 256, 0, stream>>>(pred, gt, rankinv, circ_p,
                                               circ_g, sup, out);
}

// Round 15
// 142.861 us; speedup vs baseline: 1.2170x; 1.2170x over previous
//
#include <hip/hip_runtime.h>
#include <math.h>

// ---------------------------------------------------------------------------
// PreLossSampler (N=1024):
//   out = [reg_valid | labels | max_overlaps | gt_assignment]  (4096 float32)
//
// 3 kernels (round-11 configuration — best measured of 6 NMS formulations
// tested in rounds 9-14; see session journal):
//   prep_sa   : 256x256, wave-per-element stable rank sort; writes
//               rankinv[e], sorted sbox/circ_s, circles, elementwise outs.
//   supA_sa   : 256x256, block owns 4 sorted rows; circle scan -> LDS pair
//               buffer -> dense clip eval -> LDS atomicOr -> global sup.
//   outB_fused: 256x256. Phase 1 (wave 0): greedy NMS recomputed redundantly
//               per block. Per word: LDS broadcast bc[lane]=row[W] (same-wave
//               ordering, no barrier), then 4 batches of {16 ds_read_b64 ->
//               16 VALU cndmask steps}; register rows + prefetch + butterfly
//               cross-word suppression. Keep words -> ksh[16].
//               Phase 2: pred x gt scan (sampled via rankinv bit lookup) ->
//               LDS buffer -> dense IoU3D eval -> packed u64 atomicMax ->
//               out[2], out[3].
//
// NMS floor note: the greedy scan is a 1024-step dependent chain on a single
// wave (~47 us). Alternatives measured: inline-LDS 40 us standalone (+boundary),
// readlane waterfall 50, LDS-ssup variants 73-77, cooperative grid.sync fusion
// 198-212. This configuration minimizes total wall time.
//
// Exactness: identical arithmetic to the absmax-0.0-validated rounds 6-14
// (clip, circle reject, rank predicate, batched cndmask NMS chain, max
// packing).
// ---------------------------------------------------------------------------

#define NB 1024

typedef unsigned long long u64;

__device__ __forceinline__ bool pt_in_box(float px, float py,
        float bx, float by, float bdx, float bdy, float cs, float sn) {
    float dx = px - bx, dy = py - by;
    float lx = dx * cs + dy * sn;
    float ly = dy * cs - dx * sn;
    return (fabsf(lx) <= bdx * 0.5f + 1e-5f) && (fabsf(ly) <= bdy * 0.5f + 1e-5f);
}

__device__ __forceinline__ unsigned sortbits(float f) {
    unsigned u = __float_as_uint(f + 0.0f);
    return (u & 0x80000000u) ? ~u : (u | 0x80000000u);
}

// Rotated-rectangle intersection area; reference-exact op order; all arrays
// <= 96 B, statically indexed (register-resident, zero scratch).
// Validated absmax 0.0.
__device__ float rect_inter_area(
        float ax, float ay, float adx, float ady, float ar,
        float bx, float by, float bdx, float bdy, float br) {
    float dcx = ax - bx, dcy = ay - by;
    float ra = 0.5f * sqrtf(adx * adx + ady * ady);
    float rb = 0.5f * sqrtf(bdx * bdx + bdy * bdy);
    float lim = ra + rb + 1e-3f;
    if (dcx * dcx + dcy * dcy > lim * lim) return 0.0f;

    float csa = cosf(ar), sna = sinf(ar);
    float csb = cosf(br), snb = sinf(br);
    float cax[4], cay[4], cbx[4], cby[4];
    const float SX[4] = {0.5f, 0.5f, -0.5f, -0.5f};
    const float SY[4] = {0.5f, -0.5f, -0.5f, 0.5f};
#pragma unroll
    for (int i = 0; i < 4; ++i) {
        float lx = SX[i] * adx, ly = SY[i] * ady;
        cax[i] = lx * csa - ly * sna + ax;
        cay[i] = lx * sna + ly * csa + ay;
        float mx = SX[i] * bdx, my = SY[i] * bdy;
        cbx[i] = mx * csb - my * snb + bx;
        cby[i] = mx * snb + my * csb + by;
    }

    unsigned vmask = 0u;
    float sx = 0.0f, sy = 0.0f;
#pragma unroll
    for (int i = 0; i < 4; ++i) {
        bool v = pt_in_box(cax[i], cay[i], bx, by, bdx, bdy, csb, snb);
        vmask |= v ? (1u << i) : 0u;
        sx += v ? cax[i] : 0.0f;
        sy += v ? cay[i] : 0.0f;
    }
#pragma unroll
    for (int i = 0; i < 4; ++i) {
        bool v = pt_in_box(cbx[i], cby[i], ax, ay, adx, ady, csa, sna);
        vmask |= v ? (1u << (4 + i)) : 0u;
        sx += v ? cbx[i] : 0.0f;
        sy += v ? cby[i] : 0.0f;
    }
#pragma unroll
    for (int i = 0; i < 4; ++i) {
        float a0x = cax[i], a0y = cay[i];
        float d1x = cax[(i + 1) & 3] - a0x, d1y = cay[(i + 1) & 3] - a0y;
#pragma unroll
        for (int j = 0; j < 4; ++j) {
            int s = 8 + i * 4 + j;
            float b0x = cbx[j], b0y = cby[j];
            float d2x = cbx[(j + 1) & 3] - b0x, d2y = cby[(j + 1) & 3] - b0y;
            float r0x = b0x - a0x, r0y = b0y - a0y;
            float den = d1x * d2y - d1y * d2x;
            bool nz = fabsf(den) > 1e-8f;
            float sden = nz ? den : 1.0f;
            float t = (r0x * d2y - r0y * d2x) / sden;
            float u = (r0x * d1y - r0y * d1x) / sden;
            bool ok = nz && t >= 0.0f && t <= 1.0f && u >= 0.0f && u <= 1.0f;
            float ipx = a0x + t * d1x;
            float ipy = a0y + t * d1y;
            vmask |= ok ? (1u << s) : 0u;
            sx += ok ? ipx : 0.0f;
            sy += ok ? ipy : 0.0f;
        }
    }
    int kc = __popc(vmask);
    if (kc < 3) return 0.0f;
    float ctrx = sx / (float)kc, ctry = sy / (float)kc;

    float cx24[24], cy24[24];
    unsigned h[24];
#pragma unroll
    for (int i = 0; i < 4; ++i) {
        {
            bool v = (vmask >> i) & 1u;
            float cx = v ? cax[i] - ctrx : 0.0f;
            float cy = v ? cay[i] - ctry : 0.0f;
            cx24[i] = cx; cy24[i] = cy;
            h[i] = sortbits(v ? atan2f(cy, cx) : 1e9f);
        }
        {
            bool v = (vmask >> (4 + i)) & 1u;
            float cx = v ? cbx[i] - ctrx : 0.0f;
            float cy = v ? cby[i] - ctry : 0.0f;
            cx24[4 + i] = cx; cy24[4 + i] = cy;
            h[4 + i] = sortbits(v ? atan2f(cy, cx) : 1e9f);
        }
    }
#pragma unroll
    for (int i = 0; i < 4; ++i) {
        float a0x = cax[i], a0y = cay[i];
        float d1x = cax[(i + 1) & 3] - a0x, d1y = cay[(i + 1) & 3] - a0y;
#pragma unroll
        for (int j = 0; j < 4; ++j) {
            int s = 8 + i * 4 + j;
            float b0x = cbx[j], b0y = cby[j];
            float d2x = cbx[(j + 1) & 3] - b0x, d2y = cby[(j + 1) & 3] - b0y;
            float r0x = b0x - a0x, r0y = b0y - a0y;
            float den = d1x * d2y - d1y * d2x;
            bool nz = fabsf(den) > 1e-8f;
            float sden = nz ? den : 1.0f;
            float t = (r0x * d2y - r0y * d2x) / sden;
            bool v = (vmask >> s) & 1u;
            float ipx = a0x + t * d1x;
            float ipy = a0y + t * d1y;
            float cx = v ? ipx - ctrx : 0.0f;
            float cy = v ? ipy - ctry : 0.0f;
            cx24[s] = cx; cy24[s] = cy;
            h[s] = sortbits(v ? atan2f(cy, cx) : 1e9f);
        }
    }

    int rk[24];
#pragma unroll
    for (int s = 0; s < 24; ++s) rk[s] = 0;
#pragma unroll
    for (int s = 0; s < 24; ++s) {
#pragma unroll
        for (int t = s + 1; t < 24; ++t) {
            bool a = h[s] <= h[t];
            rk[t] += a ? 1 : 0;
            rk[s] += a ? 0 : 1;
        }
    }

    float acc = 0.0f;
    float fx = 0.0f, fy = 0.0f, lx2 = 0.0f, ly2 = 0.0f;
    float pxp = 0.0f, pyp = 0.0f;
#pragma unroll
    for (int p = 0; p < 24; ++p) {
        float X = 0.0f, Y = 0.0f;
#pragma unroll
        for (int s = 0; s < 24; ++s) {
            bool m = (rk[s] == p);
            X = m ? cx24[s] : X;
            Y = m ? cy24[s] : Y;
        }
        if (p == 0) {
            fx = X; fy = Y;
        } else {
            float cr = pxp * Y - pyp * X;
            acc += (p < kc) ? cr : 0.0f;
        }
        bool e = (p == kc - 1);
        lx2 = e ? X : lx2;
        ly2 = e ? Y : ly2;
        pxp = X; pyp = Y;
    }
    acc += lx2 * fy - ly2 * fx;
    return 0.5f * fabsf(acc);
}

// ---------------------------------------------------------------------------
// prep_sa: 256x256. Wave (global id) handles element e; lane counts 16 keys;
// butterfly sum -> stable rank. Writes rankinv[e]=rank, sorted sbox/circ_s,
// circles, elementwise outs. (Validated rounds 9-14.)
// ---------------------------------------------------------------------------
__global__ __launch_bounds__(256) void prep_sa_kernel(
        const float* __restrict__ labels, const float* __restrict__ pred,
        const float* __restrict__ gt, const float* __restrict__ cls,
        float* __restrict__ out, int* __restrict__ rankinv,
        float* __restrict__ sbox, float4* __restrict__ circ_s,
        float4* __restrict__ circ_g, float4* __restrict__ circ_p) {
    int tid = threadIdx.x;
    int lane = tid & 63;
    int e = ((int)blockIdx.x * 256 + tid) >> 6;  // global wave id = element
    float ke = labels[e];
    const float4* lab4 = (const float4*)labels;
    int cntr = 0;
#pragma unroll
    for (int kk = 0; kk < 4; ++kk) {
        float4 kv = lab4[lane * 4 + kk];
        int t0 = lane * 16 + kk * 4;
        cntr += ((kv.x > ke) || (kv.x == ke && (t0 + 0) < e)) ? 1 : 0;
        cntr += ((kv.y > ke) || (kv.y == ke && (t0 + 1) < e)) ? 1 : 0;
        cntr += ((kv.z > ke) || (kv.z == ke && (t0 + 2) < e)) ? 1 : 0;
        cntr += ((kv.w > ke) || (kv.w == ke && (t0 + 3) < e)) ? 1 : 0;
    }
#pragma unroll
    for (int off = 32; off > 0; off >>= 1) cntr += __shfl_xor(cntr, off, 64);
    int rank = cntr;  // stable argsort(-labels) position of e
    if (lane < 7) sbox[rank * 8 + lane] = gt[e * 8 + lane];
    if (lane == 7) sbox[rank * 8 + 7] = 0.0f;
    if (lane == 0) {
        rankinv[e] = rank;
        float gdx = gt[e * 8 + 3], gdy = gt[e * 8 + 4];
        float4 cgc = make_float4(gt[e * 8 + 0], gt[e * 8 + 1],
                                 0.5f * sqrtf(gdx * gdx + gdy * gdy), 0.0f);
        circ_s[rank] = cgc;
        circ_g[e] = cgc;
        float pdx = pred[e * 7 + 3], pdy = pred[e * 7 + 4];
        circ_p[e] = make_float4(pred[e * 7 + 0], pred[e * 7 + 1],
                                0.5f * sqrtf(pdx * pdx + pdy * pdy), 0.0f);
        float sig = 1.0f / (1.0f + expf(-cls[e]));
        out[e] = (sig > 0.55f && ke > 0.55f) ? 1.0f : 0.0f;
        out[NB + e] = ke;
    }
}

// ---------------------------------------------------------------------------
// supA_sa: block b owns sorted rows i = b + 256v (v = wave). Circle scan ->
// LDS buffer (worst case 2556 <= 4096) -> dense clip eval -> LDS atomicOr ->
// global sup (all 16 words of all 4 rows written). Validated rounds 9-14.
// ---------------------------------------------------------------------------
__global__ __launch_bounds__(256) void supA_sa_kernel(
        const float* __restrict__ sbox, const float4* __restrict__ circ_s,
        u64* __restrict__ sup) {
    __shared__ unsigned ring[4096];
    __shared__ unsigned cnt_s;
    __shared__ unsigned sup32[128];
    int tid = threadIdx.x;
    int b = blockIdx.x;
    int lane = tid & 63;
    int wv = tid >> 6;
    if (tid == 0) cnt_s = 0u;
    for (int t = tid; t < 128; t += 256) sup32[t] = 0u;
    __syncthreads();
    {
        int i = b + (wv << 8);
        float4 A = circ_s[i];
        int j0 = ((i + 1) >> 6) << 6;
        for (int jb = j0; jb < 1024; jb += 64) {
            int j = jb + lane;
            bool q = j > i;
            if (q) {
                float4 B = circ_s[j];
                float dx = A.x - B.x, dy = A.y - B.y;
                float lim = A.z + B.z + 1e-3f;
                q = (dx * dx + dy * dy) <= lim * lim;
            }
            if (q) {
                unsigned pos = atomicAdd(&cnt_s, 1u);
                ring[pos] = (unsigned)((i << 10) | j);
            }
        }
    }
    __syncthreads();
    {
        unsigned n = cnt_s;
        for (unsigned t = tid; t < n; t += 256) {
            unsigned p = ring[t];
            int i = (p >> 10) & 1023, j = p & 1023;
            const float* A = &sbox[i * 8];
            const float* B = &sbox[j * 8];
            float inter = rect_inter_area(A[0], A[1], A[3], A[4], A[6],
                                          B[0], B[1], B[3], B[4], B[6]);
            float iou = inter / fmaxf(A[3] * A[4] + B[3] * B[4] - inter, 1e-8f);
            if (iou > 0.1f) {
                int r = (i - b) >> 8;
                atomicOr(&sup32[r * 32 + (j >> 5)], 1u << (j & 31));
            }
        }
    }
    __syncthreads();
    for (int t = tid; t < 64; t += 256) {
        int r = t >> 4, w = t & 15;
        int i = b + (r << 8);
        sup[i * 16 + w] = (u64)sup32[r * 32 + 2 * w] |
                          ((u64)sup32[r * 32 + 2 * w + 1] << 32);
    }
}

// ---------------------------------------------------------------------------
// outB_fused: phase 1 (wave 0) = greedy NMS, redundant per block. Per word:
// bc[lane]=row[W] (same-wave LDS, no barrier), 4 batches of {16 ds_read ->
// 16 cndmask chain steps}; register rows + prefetch + shfl butterfly.
// Phase 2 = pred x gt scan (sampled via rankinv bit lookup in ksh) -> LDS
// buffer -> dense IoU3D eval -> packed u64 atomicMax -> out[2], out[3].
// ---------------------------------------------------------------------------
__global__ __launch_bounds__(256) void outB_fused_kernel(
        const float* __restrict__ pred, const float* __restrict__ gt,
        const int* __restrict__ rankinv, const float4* __restrict__ circ_p,
        const float4* __restrict__ circ_g, const u64* __restrict__ sup,
        float* __restrict__ out) {
    __shared__ unsigned ring[4096];
    __shared__ unsigned cnt_s;
    __shared__ u64 bc[64];
    __shared__ u64 ksh[16];
    __shared__ u64 rm[4];
    int tid = threadIdx.x;
    int b = blockIdx.x;
    int lane = tid & 63;
    int wv = tid >> 6;
    if (tid == 0) cnt_s = 0u;
    if (tid < 4) rm[tid] = 1023ULL;  // pack(iou=0.0f, j=0)

    // ---- phase 1: NMS (wave 0 only; no barriers inside the word loop) ----
    if (tid < 64) {
        u64 acc[16];
        u64 row[16];
#pragma unroll
        for (int t = 0; t < 16; ++t) acc[t] = 0ULL;
#pragma unroll
        for (int t = 0; t < 16; ++t) row[t] = sup[(size_t)lane * 16 + t];
#pragma unroll
        for (int W = 0; W < 16; ++W) {
            u64 kwW;
            if (W == 0) {
                kwW = ~0ULL;  // no prior words
            } else {
                u64 v = acc[W];
#pragma unroll
                for (int off = 32; off > 0; off >>= 1)
                    v |= __shfl_xor(v, off, 64);
                kwW = ~v;
            }
            // broadcast this word's 64 row-words (same-wave LDS: compiler
            // orders write->read via lgkmcnt; single wave, no barrier)
            bc[lane] = row[W];
            // prefetch next word-block's rows (overlaps the chain)
            u64 rowN[16];
#pragma unroll
            for (int t = 0; t < 16; ++t) rowN[t] = 0ULL;
            if (W < 15) {
#pragma unroll
                for (int t = 0; t < 16; ++t)
                    if (t >= W + 1)
                        rowN[t] = sup[(size_t)((W + 1) * 64 + lane) * 16 + t];
            }
            // intra-word greedy: 64-step cndmask chain, reads batched 16 at
            // a time (reads are chain-independent -> one lgkm wait per batch)
#pragma unroll
            for (int g = 0; g < 4; ++g) {
                u64 rb[16];
#pragma unroll
                for (int t = 0; t < 16; ++t) rb[t] = bc[g * 16 + t];
#pragma unroll
                for (int t = 0; t < 16; ++t) {
                    int bb = g * 16 + t;
                    bool kb = (kwW >> bb) & 1ULL;
                    kwW &= kb ? ~rb[t] : ~0ULL;
                }
            }
            if (lane == 0) ksh[W] = kwW;
            bool me = (kwW >> lane) & 1ULL;
#pragma unroll
            for (int t = W + 1; t < 16; ++t) acc[t] |= me ? row[t] : 0ULL;
#pragma unroll
            for (int t = 0; t < 16; ++t) row[t] = rowN[t];
        }
    }
    __syncthreads();

    // ---- phase 2: scan + eval ----
    {
        int i = b + (wv << 8);
        float4 A = circ_p[i];
        for (int jb = 0; jb < 1024; jb += 64) {
            int j = jb + lane;
            int r = rankinv[j];
            bool q = (ksh[r >> 6] >> (r & 63)) & 1ULL;  // sampled[j]
            if (q) {
                float4 B = circ_g[j];
                float dx = A.x - B.x, dy = A.y - B.y;
                float lim = A.z + B.z + 1e-3f;
                q = (dx * dx + dy * dy) <= lim * lim;
            }
            if (q) {
                unsigned pos = atomicAdd(&cnt_s, 1u);
                ring[pos] = (unsigned)((i << 10) | j);
            }
        }
    }
    __syncthreads();
    {
        unsigned n = cnt_s;
        for (unsigned t = tid; t < n; t += 256) {
            unsigned p = ring[t];
            int i = (p >> 10) & 1023, j = p & 1023;
            float Ax = pred[i * 7 + 0], Ay = pred[i * 7 + 1], Az = pred[i * 7 + 2];
            float Adx = pred[i * 7 + 3], Ady = pred[i * 7 + 4], Adz = pred[i * 7 + 5];
            float Ar = pred[i * 7 + 6];
            float Bx = gt[j * 8 + 0], By = gt[j * 8 + 1], Bz = gt[j * 8 + 2];
            float Bdx = gt[j * 8 + 3], Bdy = gt[j * 8 + 4], Bdz = gt[j * 8 + 5];
            float Br = gt[j * 8 + 6];
            float inter = rect_inter_area(Ax, Ay, Adx, Ady, Ar,
                                          Bx, By, Bdx, Bdy, Br);
            float amax = Az + Adz * 0.5f, amin = Az - Adz * 0.5f;
            float bmax = Bz + Bdz * 0.5f, bmin = Bz - Bdz * 0.5f;
            float oh = fmaxf(fminf(amax, bmax) - fmaxf(amin, bmin), 0.0f);
            float inter3d = inter * oh;
            float va = Adx * Ady * Adz, vb = Bdx * Bdy * Bdz;
            float iou = inter3d / fmaxf(va + vb - inter3d, 1e-8f);
            u64 pk = (((u64)__float_as_uint(iou)) << 32) | (u64)(1023 - j);
            int r = (i - b) >> 8;
            atomicMax(&rm[r], pk);
        }
    }
    __syncthreads();
    if (tid < 4) {
        int i = b + (tid << 8);
        u64 v = rm[tid];
        float fv = __uint_as_float((unsigned)(v >> 32));
        int j = 1023 - (int)(v & 0xFFFFFFFFULL);
        float mo = (fv > 0.75f) ? 1.0f : ((fv < 0.25f) ? 0.0f : fv);
        out[2 * NB + i] = mo;
        out[3 * NB + i] = (float)j;
    }
}

// ---------------------------------------------------------------------------
// Workspace layout:
//   [0,       4096)    int   rankinv[1024]
//   [4096,    36864)   float sbox[1024*8]
//   [40960,   172032)  u64   sup[1024*16]
//   [172032,  188416)  float4 circ_s[1024]
//   [188416,  204800)  float4 circ_g[1024]
//   [204800,  221184)  float4 circ_p[1024]
// ---------------------------------------------------------------------------
extern "C" void kernel_launch(void* const* d_in, const int* in_sizes, int n_in,
                              void* d_out, int out_size, void* d_ws, size_t ws_size,
                              hipStream_t stream) {
    const float* labels = (const float*)d_in[0];
    const float* pred   = (const float*)d_in[1];
    const float* gt     = (const float*)d_in[2];
    const float* cls    = (const float*)d_in[3];
    float* out = (float*)d_out;

    char* ws = (char*)d_ws;
    int* rankinv   = (int*)ws;
    float* sbox    = (float*)(ws + 4096);
    u64* sup       = (u64*)(ws + 40960);
    float4* circ_s = (float4*)(ws + 172032);
    float4* circ_g = (float4*)(ws + 188416);
    float4* circ_p = (float4*)(ws + 204800);

    prep_sa_kernel<<<256, 256, 0, stream>>>(labels, pred, gt, cls, out,
                                            rankinv, sbox, circ_s, circ_g,
                                            circ_p);
    supA_sa_kernel<<<256, 256, 0, stream>>>(sbox, circ_s, sup);
    outB_fused_kernel<<<256, 256, 0, stream>>>(pred, gt, rankinv, circ_p,
                                               circ_g, sup, out);
}

// Round 16
// 137.641 us; speedup vs baseline: 1.2631x; 1.0379x over previous
//
#include <hip/hip_runtime.h>
#include <math.h>

// ---------------------------------------------------------------------------
// PreLossSampler (N=1024):
//   out = [reg_valid | labels | max_overlaps | gt_assignment]  (4096 float32)
//
// 3 kernels (round-11 config + round-16 overlap):
//   prep_sa   : 256x256, wave-per-element stable rank sort; writes
//               rankinv[e], sorted sbox/circ_s, circles, elementwise outs.
//   supA_sa   : 256x256, block owns 4 sorted rows; circle scan -> LDS pair
//               buffer -> dense clip eval -> LDS atomicOr -> global sup.
//   outB_fused: 256x256. Wave 0: greedy NMS (r11-validated: register rows +
//               prefetch + shfl butterfly + batched 64-step cndmask chain).
//               CONCURRENTLY waves 1-3: circle scan of the block's 4 pred
//               rows over all gt WITHOUT the sampled filter (the filter is
//               NMS-dependent; the circle test is not) -> ring (max 4096 =
//               capacity, overflow-free). After one barrier: all waves eval
//               the ring with the sampled test inlined (rankinv + ksh bit,
//               early continue) -> packed u64 atomicMax -> out[2], out[3].
//               Evaluated set = {circle AND sampled} — identical to r11/r15.
//
// NMS floor note: the greedy scan is a 1024-step dependent chain on a single
// wave (~45 us; best of 6 formulations tested rounds 9-14). This round hides
// the former ~13 us serial phase-2 scan inside that shadow.
//
// Exactness: identical arithmetic to the absmax-0.0-validated rounds 6-15
// (clip, circle reject, rank predicate, batched cndmask NMS chain, max
// packing; filter-order swap changes no evaluated values).
// ---------------------------------------------------------------------------

#define NB 1024

typedef unsigned long long u64;

__device__ __forceinline__ bool pt_in_box(float px, float py,
        float bx, float by, float bdx, float bdy, float cs, float sn) {
    float dx = px - bx, dy = py - by;
    float lx = dx * cs + dy * sn;
    float ly = dy * cs - dx * sn;
    return (fabsf(lx) <= bdx * 0.5f + 1e-5f) && (fabsf(ly) <= bdy * 0.5f + 1e-5f);
}

__device__ __forceinline__ unsigned sortbits(float f) {
    unsigned u = __float_as_uint(f + 0.0f);
    return (u & 0x80000000u) ? ~u : (u | 0x80000000u);
}

// Rotated-rectangle intersection area; reference-exact op order; all arrays
// <= 96 B, statically indexed (register-resident, zero scratch).
// Validated absmax 0.0.
__device__ float rect_inter_area(
        float ax, float ay, float adx, float ady, float ar,
        float bx, float by, float bdx, float bdy, float br) {
    float dcx = ax - bx, dcy = ay - by;
    float ra = 0.5f * sqrtf(adx * adx + ady * ady);
    float rb = 0.5f * sqrtf(bdx * bdx + bdy * bdy);
    float lim = ra + rb + 1e-3f;
    if (dcx * dcx + dcy * dcy > lim * lim) return 0.0f;

    float csa = cosf(ar), sna = sinf(ar);
    float csb = cosf(br), snb = sinf(br);
    float cax[4], cay[4], cbx[4], cby[4];
    const float SX[4] = {0.5f, 0.5f, -0.5f, -0.5f};
    const float SY[4] = {0.5f, -0.5f, -0.5f, 0.5f};
#pragma unroll
    for (int i = 0; i < 4; ++i) {
        float lx = SX[i] * adx, ly = SY[i] * ady;
        cax[i] = lx * csa - ly * sna + ax;
        cay[i] = lx * sna + ly * csa + ay;
        float mx = SX[i] * bdx, my = SY[i] * bdy;
        cbx[i] = mx * csb - my * snb + bx;
        cby[i] = mx * snb + my * csb + by;
    }

    unsigned vmask = 0u;
    float sx = 0.0f, sy = 0.0f;
#pragma unroll
    for (int i = 0; i < 4; ++i) {
        bool v = pt_in_box(cax[i], cay[i], bx, by, bdx, bdy, csb, snb);
        vmask |= v ? (1u << i) : 0u;
        sx += v ? cax[i] : 0.0f;
        sy += v ? cay[i] : 0.0f;
    }
#pragma unroll
    for (int i = 0; i < 4; ++i) {
        bool v = pt_in_box(cbx[i], cby[i], ax, ay, adx, ady, csa, sna);
        vmask |= v ? (1u << (4 + i)) : 0u;
        sx += v ? cbx[i] : 0.0f;
        sy += v ? cby[i] : 0.0f;
    }
#pragma unroll
    for (int i = 0; i < 4; ++i) {
        float a0x = cax[i], a0y = cay[i];
        float d1x = cax[(i + 1) & 3] - a0x, d1y = cay[(i + 1) & 3] - a0y;
#pragma unroll
        for (int j = 0; j < 4; ++j) {
            int s = 8 + i * 4 + j;
            float b0x = cbx[j], b0y = cby[j];
            float d2x = cbx[(j + 1) & 3] - b0x, d2y = cby[(j + 1) & 3] - b0y;
            float r0x = b0x - a0x, r0y = b0y - a0y;
            float den = d1x * d2y - d1y * d2x;
            bool nz = fabsf(den) > 1e-8f;
            float sden = nz ? den : 1.0f;
            float t = (r0x * d2y - r0y * d2x) / sden;
            float u = (r0x * d1y - r0y * d1x) / sden;
            bool ok = nz && t >= 0.0f && t <= 1.0f && u >= 0.0f && u <= 1.0f;
            float ipx = a0x + t * d1x;
            float ipy = a0y + t * d1y;
            vmask |= ok ? (1u << s) : 0u;
            sx += ok ? ipx : 0.0f;
            sy += ok ? ipy : 0.0f;
        }
    }
    int kc = __popc(vmask);
    if (kc < 3) return 0.0f;
    float ctrx = sx / (float)kc, ctry = sy / (float)kc;

    float cx24[24], cy24[24];
    unsigned h[24];
#pragma unroll
    for (int i = 0; i < 4; ++i) {
        {
            bool v = (vmask >> i) & 1u;
            float cx = v ? cax[i] - ctrx : 0.0f;
            float cy = v ? cay[i] - ctry : 0.0f;
            cx24[i] = cx; cy24[i] = cy;
            h[i] = sortbits(v ? atan2f(cy, cx) : 1e9f);
        }
        {
            bool v = (vmask >> (4 + i)) & 1u;
            float cx = v ? cbx[i] - ctrx : 0.0f;
            float cy = v ? cby[i] - ctry : 0.0f;
            cx24[4 + i] = cx; cy24[4 + i] = cy;
            h[4 + i] = sortbits(v ? atan2f(cy, cx) : 1e9f);
        }
    }
#pragma unroll
    for (int i = 0; i < 4; ++i) {
        float a0x = cax[i], a0y = cay[i];
        float d1x = cax[(i + 1) & 3] - a0x, d1y = cay[(i + 1) & 3] - a0y;
#pragma unroll
        for (int j = 0; j < 4; ++j) {
            int s = 8 + i * 4 + j;
            float b0x = cbx[j], b0y = cby[j];
            float d2x = cbx[(j + 1) & 3] - b0x, d2y = cby[(j + 1) & 3] - b0y;
            float r0x = b0x - a0x, r0y = b0y - a0y;
            float den = d1x * d2y - d1y * d2x;
            bool nz = fabsf(den) > 1e-8f;
            float sden = nz ? den : 1.0f;
            float t = (r0x * d2y - r0y * d2x) / sden;
            bool v = (vmask >> s) & 1u;
            float ipx = a0x + t * d1x;
            float ipy = a0y + t * d1y;
            float cx = v ? ipx - ctrx : 0.0f;
            float cy = v ? ipy - ctry : 0.0f;
            cx24[s] = cx; cy24[s] = cy;
            h[s] = sortbits(v ? atan2f(cy, cx) : 1e9f);
        }
    }

    int rk[24];
#pragma unroll
    for (int s = 0; s < 24; ++s) rk[s] = 0;
#pragma unroll
    for (int s = 0; s < 24; ++s) {
#pragma unroll
        for (int t = s + 1; t < 24; ++t) {
            bool a = h[s] <= h[t];
            rk[t] += a ? 1 : 0;
            rk[s] += a ? 0 : 1;
        }
    }

    float acc = 0.0f;
    float fx = 0.0f, fy = 0.0f, lx2 = 0.0f, ly2 = 0.0f;
    float pxp = 0.0f, pyp = 0.0f;
#pragma unroll
    for (int p = 0; p < 24; ++p) {
        float X = 0.0f, Y = 0.0f;
#pragma unroll
        for (int s = 0; s < 24; ++s) {
            bool m = (rk[s] == p);
            X = m ? cx24[s] : X;
            Y = m ? cy24[s] : Y;
        }
        if (p == 0) {
            fx = X; fy = Y;
        } else {
            float cr = pxp * Y - pyp * X;
            acc += (p < kc) ? cr : 0.0f;
        }
        bool e = (p == kc - 1);
        lx2 = e ? X : lx2;
        ly2 = e ? Y : ly2;
        pxp = X; pyp = Y;
    }
    acc += lx2 * fy - ly2 * fx;
    return 0.5f * fabsf(acc);
}

// ---------------------------------------------------------------------------
// prep_sa: 256x256. Wave (global id) handles element e; lane counts 16 keys;
// butterfly sum -> stable rank. Writes rankinv[e]=rank, sorted sbox/circ_s,
// circles, elementwise outs. (Validated rounds 9-15.)
// ---------------------------------------------------------------------------
__global__ __launch_bounds__(256) void prep_sa_kernel(
        const float* __restrict__ labels, const float* __restrict__ pred,
        const float* __restrict__ gt, const float* __restrict__ cls,
        float* __restrict__ out, int* __restrict__ rankinv,
        float* __restrict__ sbox, float4* __restrict__ circ_s,
        float4* __restrict__ circ_g, float4* __restrict__ circ_p) {
    int tid = threadIdx.x;
    int lane = tid & 63;
    int e = ((int)blockIdx.x * 256 + tid) >> 6;  // global wave id = element
    float ke = labels[e];
    const float4* lab4 = (const float4*)labels;
    int cntr = 0;
#pragma unroll
    for (int kk = 0; kk < 4; ++kk) {
        float4 kv = lab4[lane * 4 + kk];
        int t0 = lane * 16 + kk * 4;
        cntr += ((kv.x > ke) || (kv.x == ke && (t0 + 0) < e)) ? 1 : 0;
        cntr += ((kv.y > ke) || (kv.y == ke && (t0 + 1) < e)) ? 1 : 0;
        cntr += ((kv.z > ke) || (kv.z == ke && (t0 + 2) < e)) ? 1 : 0;
        cntr += ((kv.w > ke) || (kv.w == ke && (t0 + 3) < e)) ? 1 : 0;
    }
#pragma unroll
    for (int off = 32; off > 0; off >>= 1) cntr += __shfl_xor(cntr, off, 64);
    int rank = cntr;  // stable argsort(-labels) position of e
    if (lane < 7) sbox[rank * 8 + lane] = gt[e * 8 + lane];
    if (lane == 7) sbox[rank * 8 + 7] = 0.0f;
    if (lane == 0) {
        rankinv[e] = rank;
        float gdx = gt[e * 8 + 3], gdy = gt[e * 8 + 4];
        float4 cgc = make_float4(gt[e * 8 + 0], gt[e * 8 + 1],
                                 0.5f * sqrtf(gdx * gdx + gdy * gdy), 0.0f);
        circ_s[rank] = cgc;
        circ_g[e] = cgc;
        float pdx = pred[e * 7 + 3], pdy = pred[e * 7 + 4];
        circ_p[e] = make_float4(pred[e * 7 + 0], pred[e * 7 + 1],
                                0.5f * sqrtf(pdx * pdx + pdy * pdy), 0.0f);
        float sig = 1.0f / (1.0f + expf(-cls[e]));
        out[e] = (sig > 0.55f && ke > 0.55f) ? 1.0f : 0.0f;
        out[NB + e] = ke;
    }
}

// ---------------------------------------------------------------------------
// supA_sa: block b owns sorted rows i = b + 256v (v = wave). Circle scan ->
// LDS buffer (worst case 2556 <= 4096) -> dense clip eval -> LDS atomicOr ->
// global sup (all 16 words of all 4 rows written). Validated rounds 9-15.
// ---------------------------------------------------------------------------
__global__ __launch_bounds__(256) void supA_sa_kernel(
        const float* __restrict__ sbox, const float4* __restrict__ circ_s,
        u64* __restrict__ sup) {
    __shared__ unsigned ring[4096];
    __shared__ unsigned cnt_s;
    __shared__ unsigned sup32[128];
    int tid = threadIdx.x;
    int b = blockIdx.x;
    int lane = tid & 63;
    int wv = tid >> 6;
    if (tid == 0) cnt_s = 0u;
    for (int t = tid; t < 128; t += 256) sup32[t] = 0u;
    __syncthreads();
    {
        int i = b + (wv << 8);
        float4 A = circ_s[i];
        int j0 = ((i + 1) >> 6) << 6;
        for (int jb = j0; jb < 1024; jb += 64) {
            int j = jb + lane;
            bool q = j > i;
            if (q) {
                float4 B = circ_s[j];
                float dx = A.x - B.x, dy = A.y - B.y;
                float lim = A.z + B.z + 1e-3f;
                q = (dx * dx + dy * dy) <= lim * lim;
            }
            if (q) {
                unsigned pos = atomicAdd(&cnt_s, 1u);
                ring[pos] = (unsigned)((i << 10) | j);
            }
        }
    }
    __syncthreads();
    {
        unsigned n = cnt_s;
        for (unsigned t = tid; t < n; t += 256) {
            unsigned p = ring[t];
            int i = (p >> 10) & 1023, j = p & 1023;
            const float* A = &sbox[i * 8];
            const float* B = &sbox[j * 8];
            float inter = rect_inter_area(A[0], A[1], A[3], A[4], A[6],
                                          B[0], B[1], B[3], B[4], B[6]);
            float iou = inter / fmaxf(A[3] * A[4] + B[3] * B[4] - inter, 1e-8f);
            if (iou > 0.1f) {
                int r = (i - b) >> 8;
                atomicOr(&sup32[r * 32 + (j >> 5)], 1u << (j & 31));
            }
        }
    }
    __syncthreads();
    for (int t = tid; t < 64; t += 256) {
        int r = t >> 4, w = t & 15;
        int i = b + (r << 8);
        sup[i * 16 + w] = (u64)sup32[r * 32 + 2 * w] |
                          ((u64)sup32[r * 32 + 2 * w + 1] << 32);
    }
}

// ---------------------------------------------------------------------------
// outB_fused: wave 0 = r11 greedy NMS; waves 1-3 CONCURRENTLY run the
// unfiltered circle scan of the block's 4 pred rows into the ring (64
// chunk-tasks / 3 waves; max pairs 4096 = ring capacity). One barrier, then
// all waves eval with the sampled test inlined (rankinv + ksh bit).
// ---------------------------------------------------------------------------
__global__ __launch_bounds__(256) void outB_fused_kernel(
        const float* __restrict__ pred, const float* __restrict__ gt,
        const int* __restrict__ rankinv, const float4* __restrict__ circ_p,
        const float4* __restrict__ circ_g, const u64* __restrict__ sup,
        float* __restrict__ out) {
    __shared__ unsigned ring[4096];
    __shared__ unsigned cnt_s;
    __shared__ u64 bc[64];
    __shared__ u64 ksh[16];
    __shared__ u64 rm[4];
    int tid = threadIdx.x;
    int b = blockIdx.x;
    int lane = tid & 63;
    int wv = tid >> 6;
    if (tid == 0) cnt_s = 0u;
    if (tid < 4) rm[tid] = 1023ULL;  // pack(iou=0.0f, j=0)
    __syncthreads();  // cnt_s/rm visible before waves 1-3 start atomics

    if (tid < 64) {
        // ---- wave 0: NMS (r11-validated; no barriers inside) ----
        u64 acc[16];
        u64 row[16];
#pragma unroll
        for (int t = 0; t < 16; ++t) acc[t] = 0ULL;
#pragma unroll
        for (int t = 0; t < 16; ++t) row[t] = sup[(size_t)lane * 16 + t];
#pragma unroll
        for (int W = 0; W < 16; ++W) {
            u64 kwW;
            if (W == 0) {
                kwW = ~0ULL;  // no prior words
            } else {
                u64 v = acc[W];
#pragma unroll
                for (int off = 32; off > 0; off >>= 1)
                    v |= __shfl_xor(v, off, 64);
                kwW = ~v;
            }
            // broadcast this word's 64 row-words (same-wave LDS ordering)
            bc[lane] = row[W];
            // prefetch next word-block's rows (overlaps the chain)
            u64 rowN[16];
#pragma unroll
            for (int t = 0; t < 16; ++t) rowN[t] = 0ULL;
            if (W < 15) {
#pragma unroll
                for (int t = 0; t < 16; ++t)
                    if (t >= W + 1)
                        rowN[t] = sup[(size_t)((W + 1) * 64 + lane) * 16 + t];
            }
            // intra-word greedy: 64-step cndmask chain, reads batched 16
#pragma unroll
            for (int g = 0; g < 4; ++g) {
                u64 rb[16];
#pragma unroll
                for (int t = 0; t < 16; ++t) rb[t] = bc[g * 16 + t];
#pragma unroll
                for (int t = 0; t < 16; ++t) {
                    int bb = g * 16 + t;
                    bool kb = (kwW >> bb) & 1ULL;
                    kwW &= kb ? ~rb[t] : ~0ULL;
                }
            }
            if (lane == 0) ksh[W] = kwW;
            bool me = (kwW >> lane) & 1ULL;
#pragma unroll
            for (int t = W + 1; t < 16; ++t) acc[t] |= me ? row[t] : 0ULL;
#pragma unroll
            for (int t = 0; t < 16; ++t) row[t] = rowN[t];
        }
    } else {
        // ---- waves 1-3: unfiltered circle scan (NMS-independent) ----
        for (int task = wv - 1; task < 64; task += 3) {
            int r = task >> 4;
            int jb = (task & 15) << 6;
            int i = b + (r << 8);
            float4 A = circ_p[i];
            int j = jb + lane;
            float4 B = circ_g[j];
            float dx = A.x - B.x, dy = A.y - B.y;
            float lim = A.z + B.z + 1e-3f;
            if (dx * dx + dy * dy <= lim * lim) {
                unsigned pos = atomicAdd(&cnt_s, 1u);
                if (pos < 4096u) ring[pos] = (unsigned)((i << 10) | j);
            }
        }
    }
    __syncthreads();

    // ---- eval: sampled test inlined; set evaluated == {circle AND sampled}
    {
        unsigned n = min(cnt_s, 4096u);
        for (unsigned t = tid; t < n; t += 256) {
            unsigned p = ring[t];
            int i = (p >> 10) & 1023, j = p & 1023;
            int rr = rankinv[j];
            if (!((ksh[rr >> 6] >> (rr & 63)) & 1ULL)) continue;  // !sampled
            float Ax = pred[i * 7 + 0], Ay = pred[i * 7 + 1], Az = pred[i * 7 + 2];
            float Adx = pred[i * 7 + 3], Ady = pred[i * 7 + 4], Adz = pred[i * 7 + 5];
            float Ar = pred[i * 7 + 6];
            float Bx = gt[j * 8 + 0], By = gt[j * 8 + 1], Bz = gt[j * 8 + 2];
            float Bdx = gt[j * 8 + 3], Bdy = gt[j * 8 + 4], Bdz = gt[j * 8 + 5];
            float Br = gt[j * 8 + 6];
            float inter = rect_inter_area(Ax, Ay, Adx, Ady, Ar,
                                          Bx, By, Bdx, Bdy, Br);
            float amax = Az + Adz * 0.5f, amin = Az - Adz * 0.5f;
            float bmax = Bz + Bdz * 0.5f, bmin = Bz - Bdz * 0.5f;
            float oh = fmaxf(fminf(amax, bmax) - fmaxf(amin, bmin), 0.0f);
            float inter3d = inter * oh;
            float va = Adx * Ady * Adz, vb = Bdx * Bdy * Bdz;
            float iou = inter3d / fmaxf(va + vb - inter3d, 1e-8f);
            u64 pk = (((u64)__float_as_uint(iou)) << 32) | (u64)(1023 - j);
            int r = (i - b) >> 8;
            atomicMax(&rm[r], pk);
        }
    }
    __syncthreads();
    if (tid < 4) {
        int i = b + (tid << 8);
        u64 v = rm[tid];
        float fv = __uint_as_float((unsigned)(v >> 32));
        int j = 1023 - (int)(v & 0xFFFFFFFFULL);
        float mo = (fv > 0.75f) ? 1.0f : ((fv < 0.25f) ? 0.0f : fv);
        out[2 * NB + i] = mo;
        out[3 * NB + i] = (float)j;
    }
}

// ---------------------------------------------------------------------------
// Workspace layout:
//   [0,       4096)    int   rankinv[1024]
//   [4096,    36864)   float sbox[1024*8]
//   [40960,   172032)  u64   sup[1024*16]
//   [172032,  188416)  float4 circ_s[1024]
//   [188416,  204800)  float4 circ_g[1024]
//   [204800,  221184)  float4 circ_p[1024]
// ---------------------------------------------------------------------------
extern "C" void kernel_launch(void* const* d_in, const int* in_sizes, int n_in,
                              void* d_out, int out_size, void* d_ws, size_t ws_size,
                              hipStream_t stream) {
    const float* labels = (const float*)d_in[0];
    const float* pred   = (const float*)d_in[1];
    const float* gt     = (const float*)d_in[2];
    const float* cls    = (const float*)d_in[3];
    float* out = (float*)d_out;

    char* ws = (char*)d_ws;
    int* rankinv   = (int*)ws;
    float* sbox    = (float*)(ws + 4096);
    u64* sup       = (u64*)(ws + 40960);
    float4* circ_s = (float4*)(ws + 172032);
    float4* circ_g = (float4*)(ws + 188416);
    float4* circ_p = (float4*)(ws + 204800);

    prep_sa_kernel<<<256, 256, 0, stream>>>(labels, pred, gt, cls, out,
                                            rankinv, sbox, circ_s, circ_g,
                                            circ_p);
    supA_sa_kernel<<<256, 256, 0, stream>>>(sbox, circ_s, sup);
    outB_fused_kernel<<<256, 256, 0, stream>>>(pred, gt, rankinv, circ_p,
                                               circ_g, sup, out);
}

// Round 17
// 115.795 us; speedup vs baseline: 1.5014x; 1.1887x over previous
//
#include <hip/hip_runtime.h>
#include <math.h>

// ---------------------------------------------------------------------------
// PreLossSampler (N=1024):
//   out = [reg_valid | labels | max_overlaps | gt_assignment]  (4096 float32)
//
// 3 kernels (round-16 config + round-17 eval-in-shadow):
//   prep_sa   : 256x256, wave-per-element stable rank sort; writes
//               rankinv[e], sorted sbox/circ_s, circles, elementwise outs.
//   supA_sa   : 256x256, block owns 4 sorted rows; circle scan -> LDS pair
//               buffer -> dense clip eval -> LDS atomicOr -> global sup.
//   outB_fused: 256x256. Wave 0: greedy NMS (r11-validated). CONCURRENTLY
//               waves 1-3: circle scan of the block's 4 pred rows into
//               PRIVATE ring segments (1408 = worst-case, overflow-free;
//               ballot compaction, zero LDS atomics), then IMMEDIATELY eval
//               the clip for their own segment (unfiltered superset; extra
//               values discarded pre-atomicMax -> outputs unchanged),
//               storing iou per entry. After one barrier: filter pass only
//               (sampled bit test + packed u64 atomicMax) -> out[2], out[3].
//
// NMS floor note: the greedy scan is a 1024-step dependent chain on a single
// wave (~45 us; best of 6 formulations tested rounds 9-14). Rounds 16-17
// hide all of the former serial phase-2 (~13 us) inside that shadow.
//
// Exactness: identical arithmetic to the absmax-0.0-validated rounds 6-16
// (clip, circle reject, rank predicate, batched cndmask NMS chain, max
// packing; the unfiltered eval computes a superset whose extra values are
// filtered out before atomicMax — evaluated-and-kept set unchanged).
// ---------------------------------------------------------------------------

#define NB 1024
#define SEG 1408  // per-wave ring segment (>= 22 tasks x 64 lanes worst case)

typedef unsigned long long u64;

__device__ __forceinline__ bool pt_in_box(float px, float py,
        float bx, float by, float bdx, float bdy, float cs, float sn) {
    float dx = px - bx, dy = py - by;
    float lx = dx * cs + dy * sn;
    float ly = dy * cs - dx * sn;
    return (fabsf(lx) <= bdx * 0.5f + 1e-5f) && (fabsf(ly) <= bdy * 0.5f + 1e-5f);
}

__device__ __forceinline__ unsigned sortbits(float f) {
    unsigned u = __float_as_uint(f + 0.0f);
    return (u & 0x80000000u) ? ~u : (u | 0x80000000u);
}

// Rotated-rectangle intersection area; reference-exact op order; all arrays
// <= 96 B, statically indexed (register-resident, zero scratch).
// Validated absmax 0.0.
__device__ float rect_inter_area(
        float ax, float ay, float adx, float ady, float ar,
        float bx, float by, float bdx, float bdy, float br) {
    float dcx = ax - bx, dcy = ay - by;
    float ra = 0.5f * sqrtf(adx * adx + ady * ady);
    float rb = 0.5f * sqrtf(bdx * bdx + bdy * bdy);
    float lim = ra + rb + 1e-3f;
    if (dcx * dcx + dcy * dcy > lim * lim) return 0.0f;

    float csa = cosf(ar), sna = sinf(ar);
    float csb = cosf(br), snb = sinf(br);
    float cax[4], cay[4], cbx[4], cby[4];
    const float SX[4] = {0.5f, 0.5f, -0.5f, -0.5f};
    const float SY[4] = {0.5f, -0.5f, -0.5f, 0.5f};
#pragma unroll
    for (int i = 0; i < 4; ++i) {
        float lx = SX[i] * adx, ly = SY[i] * ady;
        cax[i] = lx * csa - ly * sna + ax;
        cay[i] = lx * sna + ly * csa + ay;
        float mx = SX[i] * bdx, my = SY[i] * bdy;
        cbx[i] = mx * csb - my * snb + bx;
        cby[i] = mx * snb + my * csb + by;
    }

    unsigned vmask = 0u;
    float sx = 0.0f, sy = 0.0f;
#pragma unroll
    for (int i = 0; i < 4; ++i) {
        bool v = pt_in_box(cax[i], cay[i], bx, by, bdx, bdy, csb, snb);
        vmask |= v ? (1u << i) : 0u;
        sx += v ? cax[i] : 0.0f;
        sy += v ? cay[i] : 0.0f;
    }
#pragma unroll
    for (int i = 0; i < 4; ++i) {
        bool v = pt_in_box(cbx[i], cby[i], ax, ay, adx, ady, csa, sna);
        vmask |= v ? (1u << (4 + i)) : 0u;
        sx += v ? cbx[i] : 0.0f;
        sy += v ? cby[i] : 0.0f;
    }
#pragma unroll
    for (int i = 0; i < 4; ++i) {
        float a0x = cax[i], a0y = cay[i];
        float d1x = cax[(i + 1) & 3] - a0x, d1y = cay[(i + 1) & 3] - a0y;
#pragma unroll
        for (int j = 0; j < 4; ++j) {
            int s = 8 + i * 4 + j;
            float b0x = cbx[j], b0y = cby[j];
            float d2x = cbx[(j + 1) & 3] - b0x, d2y = cby[(j + 1) & 3] - b0y;
            float r0x = b0x - a0x, r0y = b0y - a0y;
            float den = d1x * d2y - d1y * d2x;
            bool nz = fabsf(den) > 1e-8f;
            float sden = nz ? den : 1.0f;
            float t = (r0x * d2y - r0y * d2x) / sden;
            float u = (r0x * d1y - r0y * d1x) / sden;
            bool ok = nz && t >= 0.0f && t <= 1.0f && u >= 0.0f && u <= 1.0f;
            float ipx = a0x + t * d1x;
            float ipy = a0y + t * d1y;
            vmask |= ok ? (1u << s) : 0u;
            sx += ok ? ipx : 0.0f;
            sy += ok ? ipy : 0.0f;
        }
    }
    int kc = __popc(vmask);
    if (kc < 3) return 0.0f;
    float ctrx = sx / (float)kc, ctry = sy / (float)kc;

    float cx24[24], cy24[24];
    unsigned h[24];
#pragma unroll
    for (int i = 0; i < 4; ++i) {
        {
            bool v = (vmask >> i) & 1u;
            float cx = v ? cax[i] - ctrx : 0.0f;
            float cy = v ? cay[i] - ctry : 0.0f;
            cx24[i] = cx; cy24[i] = cy;
            h[i] = sortbits(v ? atan2f(cy, cx) : 1e9f);
        }
        {
            bool v = (vmask >> (4 + i)) & 1u;
            float cx = v ? cbx[i] - ctrx : 0.0f;
            float cy = v ? cby[i] - ctry : 0.0f;
            cx24[4 + i] = cx; cy24[4 + i] = cy;
            h[4 + i] = sortbits(v ? atan2f(cy, cx) : 1e9f);
        }
    }
#pragma unroll
    for (int i = 0; i < 4; ++i) {
        float a0x = cax[i], a0y = cay[i];
        float d1x = cax[(i + 1) & 3] - a0x, d1y = cay[(i + 1) & 3] - a0y;
#pragma unroll
        for (int j = 0; j < 4; ++j) {
            int s = 8 + i * 4 + j;
            float b0x = cbx[j], b0y = cby[j];
            float d2x = cbx[(j + 1) & 3] - b0x, d2y = cby[(j + 1) & 3] - b0y;
            float r0x = b0x - a0x, r0y = b0y - a0y;
            float den = d1x * d2y - d1y * d2x;
            bool nz = fabsf(den) > 1e-8f;
            float sden = nz ? den : 1.0f;
            float t = (r0x * d2y - r0y * d2x) / sden;
            bool v = (vmask >> s) & 1u;
            float ipx = a0x + t * d1x;
            float ipy = a0y + t * d1y;
            float cx = v ? ipx - ctrx : 0.0f;
            float cy = v ? ipy - ctry : 0.0f;
            cx24[s] = cx; cy24[s] = cy;
            h[s] = sortbits(v ? atan2f(cy, cx) : 1e9f);
        }
    }

    int rk[24];
#pragma unroll
    for (int s = 0; s < 24; ++s) rk[s] = 0;
#pragma unroll
    for (int s = 0; s < 24; ++s) {
#pragma unroll
        for (int t = s + 1; t < 24; ++t) {
            bool a = h[s] <= h[t];
            rk[t] += a ? 1 : 0;
            rk[s] += a ? 0 : 1;
        }
    }

    float acc = 0.0f;
    float fx = 0.0f, fy = 0.0f, lx2 = 0.0f, ly2 = 0.0f;
    float pxp = 0.0f, pyp = 0.0f;
#pragma unroll
    for (int p = 0; p < 24; ++p) {
        float X = 0.0f, Y = 0.0f;
#pragma unroll
        for (int s = 0; s < 24; ++s) {
            bool m = (rk[s] == p);
            X = m ? cx24[s] : X;
            Y = m ? cy24[s] : Y;
        }
        if (p == 0) {
            fx = X; fy = Y;
        } else {
            float cr = pxp * Y - pyp * X;
            acc += (p < kc) ? cr : 0.0f;
        }
        bool e = (p == kc - 1);
        lx2 = e ? X : lx2;
        ly2 = e ? Y : ly2;
        pxp = X; pyp = Y;
    }
    acc += lx2 * fy - ly2 * fx;
    return 0.5f * fabsf(acc);
}

// IoU3D of pred box i vs gt box j (reference-exact; validated absmax 0.0).
__device__ __forceinline__ float iou3d_pair(
        const float* __restrict__ pred, const float* __restrict__ gt,
        int i, int j) {
    float Ax = pred[i * 7 + 0], Ay = pred[i * 7 + 1], Az = pred[i * 7 + 2];
    float Adx = pred[i * 7 + 3], Ady = pred[i * 7 + 4], Adz = pred[i * 7 + 5];
    float Ar = pred[i * 7 + 6];
    float Bx = gt[j * 8 + 0], By = gt[j * 8 + 1], Bz = gt[j * 8 + 2];
    float Bdx = gt[j * 8 + 3], Bdy = gt[j * 8 + 4], Bdz = gt[j * 8 + 5];
    float Br = gt[j * 8 + 6];
    float inter = rect_inter_area(Ax, Ay, Adx, Ady, Ar, Bx, By, Bdx, Bdy, Br);
    float amax = Az + Adz * 0.5f, amin = Az - Adz * 0.5f;
    float bmax = Bz + Bdz * 0.5f, bmin = Bz - Bdz * 0.5f;
    float oh = fmaxf(fminf(amax, bmax) - fmaxf(amin, bmin), 0.0f);
    float inter3d = inter * oh;
    float va = Adx * Ady * Adz, vb = Bdx * Bdy * Bdz;
    return inter3d / fmaxf(va + vb - inter3d, 1e-8f);
}

// ---------------------------------------------------------------------------
// prep_sa: 256x256. Wave-per-element stable rank sort; rankinv, sorted
// sbox/circ_s, circles, elementwise outs. (Validated rounds 9-16.)
// ---------------------------------------------------------------------------
__global__ __launch_bounds__(256) void prep_sa_kernel(
        const float* __restrict__ labels, const float* __restrict__ pred,
        const float* __restrict__ gt, const float* __restrict__ cls,
        float* __restrict__ out, int* __restrict__ rankinv,
        float* __restrict__ sbox, float4* __restrict__ circ_s,
        float4* __restrict__ circ_g, float4* __restrict__ circ_p) {
    int tid = threadIdx.x;
    int lane = tid & 63;
    int e = ((int)blockIdx.x * 256 + tid) >> 6;  // global wave id = element
    float ke = labels[e];
    const float4* lab4 = (const float4*)labels;
    int cntr = 0;
#pragma unroll
    for (int kk = 0; kk < 4; ++kk) {
        float4 kv = lab4[lane * 4 + kk];
        int t0 = lane * 16 + kk * 4;
        cntr += ((kv.x > ke) || (kv.x == ke && (t0 + 0) < e)) ? 1 : 0;
        cntr += ((kv.y > ke) || (kv.y == ke && (t0 + 1) < e)) ? 1 : 0;
        cntr += ((kv.z > ke) || (kv.z == ke && (t0 + 2) < e)) ? 1 : 0;
        cntr += ((kv.w > ke) || (kv.w == ke && (t0 + 3) < e)) ? 1 : 0;
    }
#pragma unroll
    for (int off = 32; off > 0; off >>= 1) cntr += __shfl_xor(cntr, off, 64);
    int rank = cntr;  // stable argsort(-labels) position of e
    if (lane < 7) sbox[rank * 8 + lane] = gt[e * 8 + lane];
    if (lane == 7) sbox[rank * 8 + 7] = 0.0f;
    if (lane == 0) {
        rankinv[e] = rank;
        float gdx = gt[e * 8 + 3], gdy = gt[e * 8 + 4];
        float4 cgc = make_float4(gt[e * 8 + 0], gt[e * 8 + 1],
                                 0.5f * sqrtf(gdx * gdx + gdy * gdy), 0.0f);
        circ_s[rank] = cgc;
        circ_g[e] = cgc;
        float pdx = pred[e * 7 + 3], pdy = pred[e * 7 + 4];
        circ_p[e] = make_float4(pred[e * 7 + 0], pred[e * 7 + 1],
                                0.5f * sqrtf(pdx * pdx + pdy * pdy), 0.0f);
        float sig = 1.0f / (1.0f + expf(-cls[e]));
        out[e] = (sig > 0.55f && ke > 0.55f) ? 1.0f : 0.0f;
        out[NB + e] = ke;
    }
}

// ---------------------------------------------------------------------------
// supA_sa: block b owns sorted rows i = b + 256v (v = wave). Circle scan ->
// LDS buffer -> dense clip eval -> LDS atomicOr -> global sup.
// (Validated rounds 9-16.)
// ---------------------------------------------------------------------------
__global__ __launch_bounds__(256) void supA_sa_kernel(
        const float* __restrict__ sbox, const float4* __restrict__ circ_s,
        u64* __restrict__ sup) {
    __shared__ unsigned ring[4096];
    __shared__ unsigned cnt_s;
    __shared__ unsigned sup32[128];
    int tid = threadIdx.x;
    int b = blockIdx.x;
    int lane = tid & 63;
    int wv = tid >> 6;
    if (tid == 0) cnt_s = 0u;
    for (int t = tid; t < 128; t += 256) sup32[t] = 0u;
    __syncthreads();
    {
        int i = b + (wv << 8);
        float4 A = circ_s[i];
        int j0 = ((i + 1) >> 6) << 6;
        for (int jb = j0; jb < 1024; jb += 64) {
            int j = jb + lane;
            bool q = j > i;
            if (q) {
                float4 B = circ_s[j];
                float dx = A.x - B.x, dy = A.y - B.y;
                float lim = A.z + B.z + 1e-3f;
                q = (dx * dx + dy * dy) <= lim * lim;
            }
            if (q) {
                unsigned pos = atomicAdd(&cnt_s, 1u);
                ring[pos] = (unsigned)((i << 10) | j);
            }
        }
    }
    __syncthreads();
    {
        unsigned n = cnt_s;
        for (unsigned t = tid; t < n; t += 256) {
            unsigned p = ring[t];
            int i = (p >> 10) & 1023, j = p & 1023;
            const float* A = &sbox[i * 8];
            const float* B = &sbox[j * 8];
            float inter = rect_inter_area(A[0], A[1], A[3], A[4], A[6],
                                          B[0], B[1], B[3], B[4], B[6]);
            float iou = inter / fmaxf(A[3] * A[4] + B[3] * B[4] - inter, 1e-8f);
            if (iou > 0.1f) {
                int r = (i - b) >> 8;
                atomicOr(&sup32[r * 32 + (j >> 5)], 1u << (j & 31));
            }
        }
    }
    __syncthreads();
    for (int t = tid; t < 64; t += 256) {
        int r = t >> 4, w = t & 15;
        int i = b + (r << 8);
        sup[i * 16 + w] = (u64)sup32[r * 32 + 2 * w] |
                          ((u64)sup32[r * 32 + 2 * w + 1] << 32);
    }
}

// ---------------------------------------------------------------------------
// outB_fused: wave 0 = r11 greedy NMS. Waves 1-3: ballot-compacted circle
// scan into PRIVATE ring segments (no LDS atomics), then immediate
// unfiltered clip eval of their own segment (iou stored per entry) — all in
// the NMS shadow. Post-barrier: sampled-filter + packed u64 atomicMax only.
// ---------------------------------------------------------------------------
__global__ __launch_bounds__(256) void outB_fused_kernel(
        const float* __restrict__ pred, const float* __restrict__ gt,
        const int* __restrict__ rankinv, const float4* __restrict__ circ_p,
        const float4* __restrict__ circ_g, const u64* __restrict__ sup,
        float* __restrict__ out) {
    __shared__ unsigned ring[3 * SEG];
    __shared__ float fio[3 * SEG];
    __shared__ unsigned scnt[3];
    __shared__ u64 bc[64];
    __shared__ u64 ksh[16];
    __shared__ u64 rm[4];
    int tid = threadIdx.x;
    int b = blockIdx.x;
    int lane = tid & 63;
    int wv = tid >> 6;
    if (tid < 4) rm[tid] = 1023ULL;  // pack(iou=0.0f, j=0)
    __syncthreads();

    if (tid < 64) {
        // ---- wave 0: NMS (r11-validated; no barriers inside) ----
        u64 acc[16];
        u64 row[16];
#pragma unroll
        for (int t = 0; t < 16; ++t) acc[t] = 0ULL;
#pragma unroll
        for (int t = 0; t < 16; ++t) row[t] = sup[(size_t)lane * 16 + t];
#pragma unroll
        for (int W = 0; W < 16; ++W) {
            u64 kwW;
            if (W == 0) {
                kwW = ~0ULL;
            } else {
                u64 v = acc[W];
#pragma unroll
                for (int off = 32; off > 0; off >>= 1)
                    v |= __shfl_xor(v, off, 64);
                kwW = ~v;
            }
            bc[lane] = row[W];
            u64 rowN[16];
#pragma unroll
            for (int t = 0; t < 16; ++t) rowN[t] = 0ULL;
            if (W < 15) {
#pragma unroll
                for (int t = 0; t < 16; ++t)
                    if (t >= W + 1)
                        rowN[t] = sup[(size_t)((W + 1) * 64 + lane) * 16 + t];
            }
#pragma unroll
            for (int g = 0; g < 4; ++g) {
                u64 rb[16];
#pragma unroll
                for (int t = 0; t < 16; ++t) rb[t] = bc[g * 16 + t];
#pragma unroll
                for (int t = 0; t < 16; ++t) {
                    int bb = g * 16 + t;
                    bool kb = (kwW >> bb) & 1ULL;
                    kwW &= kb ? ~rb[t] : ~0ULL;
                }
            }
            if (lane == 0) ksh[W] = kwW;
            bool me = (kwW >> lane) & 1ULL;
#pragma unroll
            for (int t = W + 1; t < 16; ++t) acc[t] |= me ? row[t] : 0ULL;
#pragma unroll
            for (int t = 0; t < 16; ++t) row[t] = rowN[t];
        }
    } else {
        // ---- waves 1-3: private-segment circle scan + immediate eval ----
        unsigned base = (unsigned)(wv - 1) * SEG;
        unsigned mycnt = 0;  // wave-uniform
        for (int task = wv - 1; task < 64; task += 3) {
            int r = task >> 4;
            int jb = (task & 15) << 6;
            int i = b + (r << 8);
            float4 A = circ_p[i];
            int j = jb + lane;
            float4 B = circ_g[j];
            float dx = A.x - B.x, dy = A.y - B.y;
            float lim = A.z + B.z + 1e-3f;
            bool q = (dx * dx + dy * dy) <= lim * lim;
            u64 m = __ballot(q ? 1 : 0);
            if (q) {
                unsigned pos = mycnt +
                    (unsigned)__popcll(m & ((1ULL << lane) - 1ULL));
                ring[base + pos] = (unsigned)((i << 10) | j);
            }
            mycnt += (unsigned)__popcll(m);
        }
        if (lane == 0) scnt[wv - 1] = mycnt;
        // eval own segment (unfiltered; same-wave LDS write->read order)
        for (unsigned t = lane; t < mycnt; t += 64) {
            unsigned p = ring[base + t];
            int i = (p >> 10) & 1023, j = p & 1023;
            fio[base + t] = iou3d_pair(pred, gt, i, j);
        }
    }
    __syncthreads();

    // ---- filter pass: sampled test + packed atomicMax (cheap) ----
#pragma unroll 1
    for (int s = 0; s < 3; ++s) {
        unsigned n = min(scnt[s], (unsigned)SEG);
        for (unsigned t = tid; t < n; t += 256) {
            unsigned p = ring[s * SEG + t];
            int i = (p >> 10) & 1023, j = p & 1023;
            int rr = rankinv[j];
            if (!((ksh[rr >> 6] >> (rr & 63)) & 1ULL)) continue;  // !sampled
            float iou = fio[s * SEG + t];
            u64 pk = (((u64)__float_as_uint(iou)) << 32) | (u64)(1023 - j);
            atomicMax(&rm[(i - b) >> 8], pk);
        }
    }
    __syncthreads();
    if (tid < 4) {
        int i = b + (tid << 8);
        u64 v = rm[tid];
        float fv = __uint_as_float((unsigned)(v >> 32));
        int j = 1023 - (int)(v & 0xFFFFFFFFULL);
        float mo = (fv > 0.75f) ? 1.0f : ((fv < 0.25f) ? 0.0f : fv);
        out[2 * NB + i] = mo;
        out[3 * NB + i] = (float)j;
    }
}

// ---------------------------------------------------------------------------
// Workspace layout:
//   [0,       4096)    int   rankinv[1024]
//   [4096,    36864)   float sbox[1024*8]
//   [40960,   172032)  u64   sup[1024*16]
//   [172032,  188416)  float4 circ_s[1024]
//   [188416,  204800)  float4 circ_g[1024]
//   [204800,  221184)  float4 circ_p[1024]
// ---------------------------------------------------------------------------
extern "C" void kernel_launch(void* const* d_in, const int* in_sizes, int n_in,
                              void* d_out, int out_size, void* d_ws, size_t ws_size,
                              hipStream_t stream) {
    const float* labels = (const float*)d_in[0];
    const float* pred   = (const float*)d_in[1];
    const float* gt     = (const float*)d_in[2];
    const float* cls    = (const float*)d_in[3];
    float* out = (float*)d_out;

    char* ws = (char*)d_ws;
    int* rankinv   = (int*)ws;
    float* sbox    = (float*)(ws + 4096);
    u64* sup       = (u64*)(ws + 40960);
    float4* circ_s = (float4*)(ws + 172032);
    float4* circ_g = (float4*)(ws + 188416);
    float4* circ_p = (float4*)(ws + 204800);

    prep_sa_kernel<<<256, 256, 0, stream>>>(labels, pred, gt, cls, out,
                                            rankinv, sbox, circ_s, circ_g,
                                            circ_p);
    supA_sa_kernel<<<256, 256, 0, stream>>>(sbox, circ_s, sup);
    outB_fused_kernel<<<256, 256, 0, stream>>>(pred, gt, rankinv, circ_p,
                                               circ_g, sup, out);
}